// Round 19
// baseline (142.559 us; speedup 1.0000x reference)
//
#include <hip/hip_runtime.h>
#include <hip/hip_fp16.h>
#include <math.h>

#define HH 512
#define WW 512
#define BB 4
#define NPIX (BB * HH * WW)

#define HS 4                 // core rows per wave
#define NSX 9                // fused01/fused89 strips: 9 x 58
#define NBAND (HH / HS)      // 128
#define NWAVES (NSX * NBAND * BB)   // 4608
#define NBLK (NWAVES / 4)           // 1152
#define BPR (NBLK / 8)              // 144

#define NSX2 5               // sweep2 strips: 5 x 124 cols (2 px/lane)
#define NWAVES2 (NSX2 * NBAND * BB) // 2560
#define NBLK2 (NWAVES2 / 2)         // 1280 blocks x 128 threads
#define BPR2 (NBLK2 / 8)            // 160

constexpr float TAUf   = 0.01f;
constexpr float RHOf   = 1.99f;
constexpr float SIGMAf = (float)(1.0 / 0.01 / 72.0);
constexpr float INV1PT = (float)(1.0 / 1.01);

__device__ __forceinline__ float SD(float v) { return __shfl_down(v, 1, 64); }    // lane+1
__device__ __forceinline__ unsigned SDu(unsigned v) { return __shfl_down(v, 1, 64); }
__device__ __forceinline__ float SUp(float v) { return __shfl_up(v, 1, 64); }     // lane-1

// F record (uint2): .x = half2(x2, r0), .y = half2(r1, y_half)
// u record (uint2): .x = half2(u0, u1), .y = half2(u2, u3)

// ---------------------------------------------------------------------------
// sweep2: one mid iteration, 2 pixels/lane (cols wA = even, wB = wA+1).
// 16B uint4 loads/stores; shuffles only at the lane boundary (2.5/px).
// Core lanes 1..62 -> 124 cols/strip, 5 strips. XCD band-ownership matches
// fused01/fused89 (same t2 = band + 128*b extraction).
// ---------------------------------------------------------------------------
__global__ __launch_bounds__(128) void sweep2(
    const int* __restrict__ ths_p,
    const uint2* __restrict__ f_in, const uint2* __restrict__ u_in,
    uint2* __restrict__ f_out, uint2* __restrict__ u_out)
{
    const int tid  = threadIdx.x;
    const int lane = tid & 63;
    const int bid  = blockIdx.x;
    const int wid  = (((bid & 7) * BPR2) + (bid >> 3)) * 2 + (tid >> 6);
    const int sx   = wid % NSX2;
    const int t2   = wid / NSX2;
    const int band = t2 & (NBAND - 1);
    const int b    = t2 / NBAND;
    const int R0   = band * HS;
    const int wA   = sx * 124 - 2 + 2 * lane;   // even -> uint4 16B-aligned
    const int wB   = wA + 1;
    const int boff = b * (HH * WW);
    const bool okA = ((unsigned)wA) < (unsigned)WW;   // wA even -> implies wB<WW
    const float mAA = (wA >= 1 && wA < WW) ? 1.f : 0.f;
    const float mAB = (wB >= 1 && wB < WW) ? 1.f : 0.f;
    const float mBA = (wA >= 0 && wA < WW - 1) ? 1.f : 0.f;
    const float mBB = (wB >= 0 && wB < WW - 1) ? 1.f : 0.f;
    const bool cok = (lane >= 1) && (lane <= 62) && okA;

    const float ths  = (float)ths_p[0];
    const float tl1_ = TAUf * (ths * 0.1f);
    const float l2_  = ths * 0.15f;

    // rings, per column A/B
    float uf0A[4], uf1A[4], uf2A[4], uf3A[4];
    float uf0B[4], uf1B[4], uf2B[4], uf3B[4];
    unsigned u12A[4];                 // packed (u1A,u2A) for the boundary shuffle
    float i0A[2], i1A[2], i0B[2], i1B[2];
    float sA[2], sB[2], t1A[2], t1B[2];
    float v0A[4], v0B[4], v1A[2], v1B[2];
    #pragma unroll
    for (int q = 0; q < 4; ++q) {
        uf0A[q]=uf1A[q]=uf2A[q]=uf3A[q]=0.f;
        uf0B[q]=uf1B[q]=uf2B[q]=uf3B[q]=0.f;
        v0A[q]=v0B[q]=0.f; u12A[q]=0u;
    }
    i0A[0]=i0A[1]=i1A[0]=i1A[1]=0.f;
    i0B[0]=i0B[1]=i1B[0]=i1B[1]=0.f;
    sA[0]=sA[1]=sB[0]=sB[1]=0.f;
    t1A[0]=t1A[1]=t1B[0]=t1B[1]=0.f;
    v1A[0]=v1A[1]=v1B[0]=v1B[1]=0.f;

    auto uload2 = [&](int row) -> uint4 {
        uint4 z; z.x=z.y=z.z=z.w=0u;
        if (((unsigned)row) < (unsigned)HH && okA)
            z = *(const uint4*)(u_in + (size_t)(boff + row * WW + wA));
        return z;
    };
    auto fload2 = [&](int row) -> uint4 {
        uint4 z; z.x=z.y=z.z=z.w=0u;
        if (((unsigned)row) < (unsigned)HH && okA)
            z = *(const uint4*)(f_in + (size_t)(boff + row * WW + wA));
        return z;
    };
    auto unpk2 = [&](int slot, uint4 raw) {
        __half2 a0 = *(reinterpret_cast<__half2*>(&raw.x));
        __half2 a1 = *(reinterpret_cast<__half2*>(&raw.y));
        __half2 b0 = *(reinterpret_cast<__half2*>(&raw.z));
        __half2 b1 = *(reinterpret_cast<__half2*>(&raw.w));
        uf0A[slot] = __low2float(a0); uf1A[slot] = __high2float(a0);
        uf2A[slot] = __low2float(a1); uf3A[slot] = __high2float(a1);
        uf0B[slot] = __low2float(b0); uf1B[slot] = __high2float(b0);
        uf2B[slot] = __low2float(b1); uf3B[slot] = __high2float(b1);
        u12A[slot] = (raw.x >> 16) | (raw.y << 16);
    };
    auto compI2 = [&](int rr, int islot, int c, int d, int uu_) {
        if (((unsigned)rr) < (unsigned)HH) {
            float hD  = (rr < HH - 1) ? 1.f : 0.f;
            unsigned pp = SDu(u12A[c]);              // (u1,u2) of col wB+1
            __half2 ph = *(reinterpret_cast<__half2*>(&pp));
            float u1nB = __low2float(ph);
            float u2nB = __high2float(ph);
            // col A: neighbor col wB in-lane
            i0A[islot] = uf0A[c] - uf0A[d] - uf1B[c] + mAA * uf1A[c];
            i1A[islot] = uf2A[c] - uf2B[c] - hD * uf3A[c] + uf3A[uu_];
            // col B: neighbor via shuffle
            i0B[islot] = uf0B[c] - uf0B[d] - u1nB + mAB * uf1B[c];
            i1B[islot] = uf2B[c] - u2nB - hD * uf3B[c] + uf3B[uu_];
        } else {
            i0A[islot]=0.f; i1A[islot]=0.f; i0B[islot]=0.f; i1B[islot]=0.f;
        }
    };

    // ---- prologue (2-deep prefetch) ----
    unpk2(1, uload2(R0 - 3));
    unpk2(2, uload2(R0 - 2));
    unpk2(3, uload2(R0 - 1));
    compI2(R0 - 2, 0, 2, 3, 1);
    uint4 puA = uload2(R0);
    uint4 puB = uload2(R0 + 1);
    uint4 pfA = fload2(R0 - 1);
    uint4 pfB = fload2(R0);

    #pragma unroll
    for (int k = 0; k < HS + 3; ++k) {
        const int rr = R0 - 1 + k;

        unpk2(k & 3, puA);
        puA = puB;
        if (k <= HS) puB = uload2(R0 + k + 2);

        __half2 fa0 = *(reinterpret_cast<__half2*>(&pfA.x));
        __half2 fa1 = *(reinterpret_cast<__half2*>(&pfA.y));
        __half2 fb0 = *(reinterpret_cast<__half2*>(&pfA.z));
        __half2 fb1 = *(reinterpret_cast<__half2*>(&pfA.w));
        float x2A = __low2float(fa0), r0A_ = __high2float(fa0);
        float r1A_ = __low2float(fa1), yA = __high2float(fa1);
        float x2B = __low2float(fb0), r0B_ = __high2float(fb0);
        float r1B_ = __low2float(fb1), yB = __high2float(fb1);
        unsigned yrawA = pfA.y >> 16;
        unsigned yrawB = pfA.w >> 16;
        pfA = pfB;
        if (k <= HS) pfB = fload2(R0 + k + 1);

        compI2(rr, (k + 1) & 1, (k + 3) & 3, k & 3, (k + 2) & 3);

        // compS both columns
        float sNA, t0NA, t1NA, sNB, t0NB, t1NB;
        uint2 FAo, FBo; FAo.x=FAo.y=FBo.x=FBo.y=0u;
        {
            const int isc = (k + 1) & 1, isp = k & 1;
            if (((unsigned)rr) < (unsigned)HH) {
                float hD = (rr < HH - 1) ? 1.f : 0.f;
                float i0cA = i0A[isc], i1cA = i1A[isc], i1uA = i1A[isp];
                float i0cB = i0B[isc], i1cB = i1B[isc], i1uB = i1B[isp];
                float i0lA = SUp(i0B[isc]);     // i0(wA-1) = lane-1's colB
                float i0lB = i0A[isc];          // i0(wB-1) = own colA
                float naA = TAUf * (mAA * i0lA - mBA * i0cA + i1uA - hD * i1cA);
                float naB = TAUf * (mAB * i0lB - mBB * i0cB + i1uB - hD * i1cB);
                float xA = (x2A - naA + TAUf * yA) * INV1PT;
                float xB = (x2B - naB + TAUf * yB) * INV1PT;
                float rrA0 = r0A_ + TAUf * i0cA, rrA1 = r1A_ + TAUf * i1cA;
                float rrB0 = r0B_ + TAUf * i0cB, rrB1 = r1B_ + TAUf * i1cB;
                float dA = rrA0*rrA0 + rrA1*rrA1;
                float dB = rrB0*rrB0 + rrB1*rrB1;
                float riA = fminf(tl1_ * __builtin_amdgcn_rsqf(dA), 1.0f);
                float riB = fminf(tl1_ * __builtin_amdgcn_rsqf(dB), 1.0f);
                float r0nA = rrA0 - rrA0 * riA, r1nA = rrA1 - rrA1 * riA;
                float r0nB = rrB0 - rrB0 * riB, r1nB = rrB1 - rrB1 * riB;
                sNA  = 2.f * xA - x2A; t0NA = 2.f * r0nA - r0A_; t1NA = 2.f * r1nA - r1A_;
                sNB  = 2.f * xB - x2B; t0NB = 2.f * r0nB - r0B_; t1NB = 2.f * r1nB - r1B_;
                __half2 la = __floats2half2_rn(x2A + RHOf * (xA - x2A),
                                               r0A_ + RHOf * (r0nA - r0A_));
                unsigned r1bA = (unsigned)__half_as_ushort(
                    __float2half(r1A_ + RHOf * (r1nA - r1A_)));
                __half2 lb = __floats2half2_rn(x2B + RHOf * (xB - x2B),
                                               r0B_ + RHOf * (r0nB - r0B_));
                unsigned r1bB = (unsigned)__half_as_ushort(
                    __float2half(r1B_ + RHOf * (r1nB - r1B_)));
                FAo.x = *(unsigned*)&la; FAo.y = r1bA | (yrawA << 16);
                FBo.x = *(unsigned*)&lb; FBo.y = r1bB | (yrawB << 16);
                if ((k >= 1 && k <= HS) && cok) {
                    int idx = boff + rr * WW + wA;
                    uint4 st; st.x = FAo.x; st.y = FAo.y; st.z = FBo.x; st.w = FBo.y;
                    *(uint4*)(f_out + (size_t)idx) = st;
                }
            } else {
                sNA=0.f; t0NA=0.f; t1NA=0.f; sNB=0.f; t0NB=0.f; t1NB=0.f;
            }
        }

        // v-ring updates
        {
            float sPA = sA[k & 1], t1PA = t1A[k & 1];
            float sPB = sB[k & 1], t1PB = t1B[k & 1];
            float hDm1 = (rr < HH) ? 1.f : 0.f;
            float sdA = SD(sNA);                    // s(wB+1) = lane+1's colA
            v0A[(k + 3) & 3] = mBA * (sNB - sNA) - t0NA;
            v0B[(k + 3) & 3] = mBB * (sdA - sNB) - t0NB;
            v1A[k & 1] = hDm1 * (sNA - sPA) - t1PA;
            v1B[k & 1] = hDm1 * (sNB - sPB) - t1PB;
            sA[(k + 1) & 1] = sNA; sB[(k + 1) & 1] = sNB;
            t1A[(k + 1) & 1] = t1NA; t1B[(k + 1) & 1] = t1NB;
        }

        if (k >= 3) {
            const int ro = R0 - 3 + k;
            const int v0c_s = (k + 1) & 3, v0u_s = k & 3;
            const int v1c_s = (k + 1) & 1, v1d_s = k & 1;
            const int us = (k + 1) & 3;
            float hD  = (ro < HH - 1) ? 1.f : 0.f;
            float v0cA = v0A[v0c_s], v0uA = v0A[v0u_s];
            float v1cA = v1A[v1c_s], v1dA = v1A[v1d_s];
            float v0cB = v0B[v0c_s], v0uB = v0B[v0u_s];
            float v1cB = v1B[v1c_s], v1dB = v1B[v1d_s];
            float v0lA = SUp(v0B[v0c_s]);      // v0(wA-1) = lane-1's colB
            float v1lA = SUp(v1B[v1c_s]);
            float v0lB = v0cA;                  // v0(wB-1) = own colA
            float v1lB = v1cA;
            float G0A = v0cA - v0uA;
            float G1A = mAA * (v0cA - v0lA);
            float G2A = v1cA - mAA * v1lA;
            float G3A = hD * (v1dA - v1cA);
            float G0B = v0cB - v0uB;
            float G1B = mAB * (v0cB - v0lB);
            float G2B = v1cB - mAB * v1lB;
            float G3B = hD * (v1dB - v1cB);
            float u0A_ = uf0A[us], u1A_ = uf1A[us], u2A_ = uf2A[us], u3A_ = uf3A[us];
            float u0B_ = uf0B[us], u1B_ = uf1B[us], u2B_ = uf2B[us], u3B_ = uf3B[us];
            float a0 = u0A_ + SIGMAf * G0A, a1 = u1A_ + SIGMAf * G1A;
            float a2 = u2A_ + SIGMAf * G2A, a3 = u3A_ + SIGMAf * G3A;
            float b0 = u0B_ + SIGMAf * G0B, b1 = u1B_ + SIGMAf * G1B;
            float b2 = u2B_ + SIGMAf * G2B, b3 = u3B_ + SIGMAf * G3B;
            float dA = a0*a0 + a1*a1 + a2*a2 + a3*a3;
            float dB = b0*b0 + b1*b1 + b2*b2 + b3*b3;
            float uiA = fminf(l2_ * __builtin_amdgcn_rsqf(dA), 1.0f);
            float uiB = fminf(l2_ * __builtin_amdgcn_rsqf(dB), 1.0f);
            if (cok) {
                int idx = boff + ro * WW + wA;
                __half2 la = __floats2half2_rn(u0A_ + RHOf * (a0 * uiA - u0A_),
                                               u1A_ + RHOf * (a1 * uiA - u1A_));
                __half2 ha = __floats2half2_rn(u2A_ + RHOf * (a2 * uiA - u2A_),
                                               u3A_ + RHOf * (a3 * uiA - u3A_));
                __half2 lb = __floats2half2_rn(u0B_ + RHOf * (b0 * uiB - u0B_),
                                               u1B_ + RHOf * (b1 * uiB - u1B_));
                __half2 hb = __floats2half2_rn(u2B_ + RHOf * (b2 * uiB - u2B_),
                                               u3B_ + RHOf * (b3 * uiB - u3B_));
                uint4 st;
                st.x = *(unsigned*)&la; st.y = *(unsigned*)&ha;
                st.z = *(unsigned*)&lb; st.w = *(unsigned*)&hb;
                *(uint4*)(u_out + (size_t)idx) = st;
            }
        }
    }
}

// ---------------------------------------------------------------------------
// fused01: iterations 0 (analytic) + 1. 58-col cores (lanes 3..60).
// ---------------------------------------------------------------------------
__global__ __launch_bounds__(256) void fused01(
    const float* __restrict__ y, const int* __restrict__ ths_p,
    uint2* __restrict__ f_out, uint2* __restrict__ u_out)
{
    const int tid  = threadIdx.x;
    const int lane = tid & 63;
    const int bid  = blockIdx.x;
    const int wid  = (((bid & 7) * BPR) + (bid >> 3)) * 4 + (tid >> 6);
    const int sx   = wid % NSX;
    const int t2   = wid / NSX;
    const int band = t2 & (NBAND - 1);
    const int b    = t2 / NBAND;
    const int R0   = band * HS;
    const int w    = sx * 58 - 3 + lane;
    const int boff = b * (HH * WW);
    const bool wok = ((unsigned)w) < (unsigned)WW;
    const float mA = (w >= 1 && w < WW) ? 1.f : 0.f;
    const float mB = (w >= 0 && w < WW - 1) ? 1.f : 0.f;
    const bool cok = (lane >= 3) && (lane <= 60) && (w < WW);

    const float ths  = (float)ths_p[0];
    const float tl1_ = TAUf * (ths * 0.1f);
    const float l2_  = ths * 0.15f;

    float p0r[4];
    float p1r[2];
    float yD1 = 0.f, yD2 = 0.f, yD3 = 0.f;

    float uf0[4], uf1[4], uf2[4], uf3[4];
    unsigned u12r[4];
    float i0r[2], i1r[2];
    float sr[2], t1r[2];
    float v0r[4], v1r[2];
    #pragma unroll
    for (int q = 0; q < 4; ++q) {
        uf0[q]=uf1[q]=uf2[q]=uf3[q]=0.f; v0r[q]=0.f; u12r[q]=0u; p0r[q]=0.f;
    }
    i0r[0]=i0r[1]=i1r[0]=i1r[1]=0.f;
    sr[0]=sr[1]=0.f; t1r[0]=t1r[1]=0.f; v1r[0]=v1r[1]=0.f; p1r[0]=p1r[1]=0.f;

    auto yload = [&](int row) -> float {
        return (((unsigned)row) < (unsigned)HH && wok)
                   ? y[boff + row * WW + w] : 0.f;
    };
    auto unpk = [&](int slot, uint2 raw) {
        __half2 lo = *(reinterpret_cast<__half2*>(&raw.x));
        __half2 hi = *(reinterpret_cast<__half2*>(&raw.y));
        uf0[slot] = __low2float(lo); uf1[slot] = __high2float(lo);
        uf2[slot] = __low2float(hi); uf3[slot] = __high2float(hi);
        u12r[slot] = (raw.x >> 16) | (raw.y << 16);
    };
    auto compI = [&](int rr, int islot, int c, int d, int uu_) {
        if (((unsigned)rr) < (unsigned)HH) {
            float hD  = (rr < HH - 1) ? 1.f : 0.f;
            unsigned pp = SDu(u12r[c]);
            __half2 ph = *(reinterpret_cast<__half2*>(&pp));
            float u1n = __low2float(ph);
            float u2n = __high2float(ph);
            i0r[islot] = uf0[c] - uf0[d] - u1n + mA * uf1[c];
            i1r[islot] = uf2[c] - u2n - hD * uf3[c] + uf3[uu_];
        } else { i0r[islot] = 0.f; i1r[islot] = 0.f; }
    };

    float pyA = yload(R0 - 4);
    float pyB = yload(R0 - 3);

    #pragma unroll
    for (int j = 0; j < HS + 9; ++j) {
        const int p = R0 - 4 + j;
        float yp = pyA; pyA = pyB;
        if (j <= HS + 6) pyB = yload(R0 - 2 + j);

        p0r[j & 3]       = mB * (SD(yp) - yp);
        p1r[(j + 1) & 1] = ((p < HH) ? 1.f : 0.f) * (yp - yD1);

        if (j >= 3) {
            const int ro = R0 - 6 + j;
            float hD  = (ro < HH - 1) ? 1.f : 0.f;
            float v0c = p0r[(j + 2) & 3], v0u = p0r[(j + 1) & 3];
            float v1c = p1r[j & 1],       v1d = p1r[(j + 1) & 1];
            float G0 = v0c - v0u;
            float G1 = mA * (v0c - SUp(v0c));
            float G2 = v1c - mA * SUp(v1c);
            float G3 = hD * (v1d - v1c);
            float uu0 = SIGMAf * G0, uu1 = SIGMAf * G1;
            float uu2 = SIGMAf * G2, uu3 = SIGMAf * G3;
            float d = uu0*uu0 + uu1*uu1 + uu2*uu2 + uu3*uu3;
            float ui = fminf(l2_ * __builtin_amdgcn_rsqf(d), 1.0f);
            __half2 lo = __floats2half2_rn(RHOf * (uu0 * ui), RHOf * (uu1 * ui));
            __half2 hi = __floats2half2_rn(RHOf * (uu2 * ui), RHOf * (uu3 * ui));
            uint2 st; st.x = *(unsigned*)&lo; st.y = *(unsigned*)&hi;
            unpk((j + 2) & 3, st);
        }

        if (j == 5) compI(R0 - 2, 0, 2, 3, 1);

        if (j >= 6) {
            const int k  = j - 6;
            const int rr = R0 - 1 + k;
            __half yh = __float2half(yD3);
            float yv  = __half2float(yh);
            unsigned yraw = (unsigned)__half_as_ushort(yh);

            compI(rr, (k + 1) & 1, (k + 3) & 3, k & 3, (k + 2) & 3);

            float sN, t0N, t1N;
            {
                const bool coreRow = (k >= 1 && k <= HS);
                if (((unsigned)rr) < (unsigned)HH) {
                    float hD = (rr < HH - 1) ? 1.f : 0.f;
                    float i0c = i0r[(k + 1) & 1], i1c = i1r[(k + 1) & 1];
                    float i1u = i1r[k & 1];
                    float i0l = SUp(i0c);
                    float na = TAUf * (mA * i0l - mB * i0c + i1u - hD * i1c);
                    float x = (yv - na + TAUf * yv) * INV1PT;
                    float rr0 = TAUf * i0c;
                    float rr1 = TAUf * i1c;
                    float d2 = rr0*rr0 + rr1*rr1;
                    float rinv = fminf(tl1_ * __builtin_amdgcn_rsqf(d2), 1.0f);
                    float r0 = rr0 - rr0 * rinv;
                    float r1 = rr1 - rr1 * rinv;
                    sN  = 2.f * x - yv;
                    t0N = 2.f * r0;
                    t1N = 2.f * r1;
                    if (coreRow && cok) {
                        int idx = boff + rr * WW + w;
                        __half2 lo2 = __floats2half2_rn(yv + RHOf * (x - yv),
                                                        RHOf * r0);
                        unsigned r1b = (unsigned)__half_as_ushort(
                            __float2half(RHOf * r1));
                        uint2 st2; st2.x = *(unsigned*)&lo2;
                        st2.y = r1b | (yraw << 16);
                        f_out[(size_t)idx] = st2;
                    }
                } else { sN = 0.f; t0N = 0.f; t1N = 0.f; }
            }

            {
                float sPrev  = sr[k & 1];
                float t1Prev = t1r[k & 1];
                float hDm1   = (rr < HH) ? 1.f : 0.f;
                v0r[(k + 3) & 3] = mB * (SD(sN) - sN) - t0N;
                v1r[k & 1]       = hDm1 * (sN - sPrev) - t1Prev;
                sr[(k + 1) & 1]  = sN;
                t1r[(k + 1) & 1] = t1N;
            }

            if (k >= 3) {
                const int ro = R0 - 3 + k;
                float hD  = (ro < HH - 1) ? 1.f : 0.f;
                float v0c = v0r[(k + 1) & 3], v0u = v0r[k & 3];
                float v1c = v1r[(k + 1) & 1], v1d = v1r[k & 1];
                float v0l = SUp(v0c);
                float v1l = SUp(v1c);
                float G0 = v0c - v0u;
                float G1 = mA * (v0c - v0l);
                float G2 = v1c - mA * v1l;
                float G3 = hD * (v1d - v1c);
                const int us = (k + 1) & 3;
                float u0v = uf0[us], u1v = uf1[us], u2v = uf2[us], u3v = uf3[us];
                float uu0 = u0v + SIGMAf * G0;
                float uu1 = u1v + SIGMAf * G1;
                float uu2 = u2v + SIGMAf * G2;
                float uu3 = u3v + SIGMAf * G3;
                float d = uu0*uu0 + uu1*uu1 + uu2*uu2 + uu3*uu3;
                float ui = fminf(l2_ * __builtin_amdgcn_rsqf(d), 1.0f);
                if (cok) {
                    int idx = boff + ro * WW + w;
                    __half2 lo = __floats2half2_rn(u0v + RHOf * (uu0 * ui - u0v),
                                                   u1v + RHOf * (uu1 * ui - u1v));
                    __half2 hi = __floats2half2_rn(u2v + RHOf * (uu2 * ui - u2v),
                                                   u3v + RHOf * (uu3 * ui - u3v));
                    uint2 st; st.x = *(unsigned*)&lo; st.y = *(unsigned*)&hi;
                    u_out[(size_t)idx] = st;
                }
            }
        }

        yD3 = yD2; yD2 = yD1; yD1 = yp;
    }
}

// ---------------------------------------------------------------------------
// fused89: iter 8 (full mid, producer P) + iter 9 (x-only, consumer C).
// ---------------------------------------------------------------------------
__global__ __launch_bounds__(256) void fused89(
    const int* __restrict__ ths_p,
    const uint2* __restrict__ f_in, const uint2* __restrict__ u_in,
    float* __restrict__ xout)
{
    const int tid  = threadIdx.x;
    const int lane = tid & 63;
    const int bid  = blockIdx.x;
    const int wid  = (((bid & 7) * BPR) + (bid >> 3)) * 4 + (tid >> 6);
    const int sx   = wid % NSX;
    const int t2   = wid / NSX;
    const int band = t2 & (NBAND - 1);
    const int b    = t2 / NBAND;
    const int R0   = band * HS;
    const int R0p  = R0 - 2;
    const int w    = sx * 58 - 3 + lane;
    const int boff = b * (HH * WW);
    const bool wok = ((unsigned)w) < (unsigned)WW;
    const float mA = (w >= 1 && w < WW) ? 1.f : 0.f;
    const float mB = (w >= 0 && w < WW - 1) ? 1.f : 0.f;
    const bool cokC = (lane >= 3) && (lane <= 60) && (w < WW);

    const float ths  = (float)ths_p[0];
    const float tl1_ = TAUf * (ths * 0.1f);
    const float l2_  = ths * 0.15f;

    constexpr int HSp = HS + 3;   // 7

    float uf0[4], uf1[4], uf2[4], uf3[4];
    unsigned u12r[4];
    float i0r[2], i1r[2];
    float sr[2], t1r[2];
    float v0r[4], v1r[2];
    float cf0[4], cf1[4], cf2[4], cf3[4];
    unsigned c12[4];
    float ci0[2], ci1[2];
    uint2 fmid[4];
    #pragma unroll
    for (int q = 0; q < 4; ++q) {
        uf0[q]=uf1[q]=uf2[q]=uf3[q]=0.f; v0r[q]=0.f; u12r[q]=0u;
        cf0[q]=cf1[q]=cf2[q]=cf3[q]=0.f; c12[q]=0u;
        fmid[q].x = 0u; fmid[q].y = 0u;
    }
    i0r[0]=i0r[1]=i1r[0]=i1r[1]=0.f;
    ci0[0]=ci0[1]=ci1[0]=ci1[1]=0.f;
    sr[0]=sr[1]=0.f; t1r[0]=t1r[1]=0.f; v1r[0]=v1r[1]=0.f;

    auto uload = [&](int row) -> uint2 {
        uint2 z; z.x = 0u; z.y = 0u;
        if (((unsigned)row) < (unsigned)HH && wok)
            z = u_in[(size_t)(boff + row * WW + w)];
        return z;
    };
    auto fload = [&](int row) -> uint2 {
        uint2 z; z.x = 0u; z.y = 0u;
        if (((unsigned)row) < (unsigned)HH && wok)
            z = f_in[(size_t)(boff + row * WW + w)];
        return z;
    };
    auto unpk = [&](int slot, uint2 raw) {
        __half2 lo = *(reinterpret_cast<__half2*>(&raw.x));
        __half2 hi = *(reinterpret_cast<__half2*>(&raw.y));
        uf0[slot] = __low2float(lo); uf1[slot] = __high2float(lo);
        uf2[slot] = __low2float(hi); uf3[slot] = __high2float(hi);
        u12r[slot] = (raw.x >> 16) | (raw.y << 16);
    };
    auto compI = [&](int rr, int islot, int c, int d, int uu_) {
        if (((unsigned)rr) < (unsigned)HH) {
            float hD  = (rr < HH - 1) ? 1.f : 0.f;
            unsigned pp = SDu(u12r[c]);
            __half2 ph = *(reinterpret_cast<__half2*>(&pp));
            float u1n = __low2float(ph);
            float u2n = __high2float(ph);
            i0r[islot] = uf0[c] - uf0[d] - u1n + mA * uf1[c];
            i1r[islot] = uf2[c] - u2n - hD * uf3[c] + uf3[uu_];
        } else { i0r[islot] = 0.f; i1r[islot] = 0.f; }
    };
    auto cunpk = [&](int slot, uint2 raw) {
        __half2 lo = *(reinterpret_cast<__half2*>(&raw.x));
        __half2 hi = *(reinterpret_cast<__half2*>(&raw.y));
        cf0[slot] = __low2float(lo); cf1[slot] = __high2float(lo);
        cf2[slot] = __low2float(hi); cf3[slot] = __high2float(hi);
        c12[slot] = (raw.x >> 16) | (raw.y << 16);
    };
    auto ccompI = [&](int rr, int islot, int c, int d, int uu_) {
        if (((unsigned)rr) < (unsigned)HH) {
            float hD  = (rr < HH - 1) ? 1.f : 0.f;
            unsigned pp = SDu(c12[c]);
            __half2 ph = *(reinterpret_cast<__half2*>(&pp));
            float u1n = __low2float(ph);
            float u2n = __high2float(ph);
            ci0[islot] = cf0[c] - cf0[d] - u1n + mA * cf1[c];
            ci1[islot] = cf2[c] - u2n - hD * cf3[c] + cf3[uu_];
        } else { ci0[islot] = 0.f; ci1[islot] = 0.f; }
    };

    unpk(1, uload(R0p - 3));
    unpk(2, uload(R0p - 2));
    unpk(3, uload(R0p - 1));
    compI(R0p - 2, 0, 2, 3, 1);
    uint2 puA = uload(R0p);
    uint2 puB = uload(R0p + 1);
    uint2 pfA = fload(R0p - 1);
    uint2 pfB = fload(R0p);

    #pragma unroll
    for (int J = 0; J < HSp + 3; ++J) {       // J = 0..9
        const int rp = R0p - 1 + J;

        unpk(J & 3, puA);
        puA = puB;
        if (J <= HSp) puB = uload(R0p + J + 2);
        __half2 flo = *(reinterpret_cast<__half2*>(&pfA.x));
        __half2 fhi = *(reinterpret_cast<__half2*>(&pfA.y));
        float x2v  = __low2float(flo);
        float r20v = __high2float(flo);
        float r21v = __low2float(fhi);
        float yv   = __high2float(fhi);
        unsigned yraw = pfA.y >> 16;
        pfA = pfB;
        if (J <= HSp) pfB = fload(R0p + J + 1);

        compI(rp, (J + 1) & 1, (J + 3) & 3, J & 3, (J + 2) & 3);

        float sN, t0N, t1N;
        if (((unsigned)rp) < (unsigned)HH) {
            float hD = (rp < HH - 1) ? 1.f : 0.f;
            float i0c = i0r[(J + 1) & 1], i1c = i1r[(J + 1) & 1];
            float i1u = i1r[J & 1];
            float i0l = SUp(i0c);
            float na = TAUf * (mA * i0l - mB * i0c + i1u - hD * i1c);
            float x = (x2v - na + TAUf * yv) * INV1PT;
            float rr0 = r20v + TAUf * i0c;
            float rr1 = r21v + TAUf * i1c;
            float d = rr0 * rr0 + rr1 * rr1;
            float rinv = fminf(tl1_ * __builtin_amdgcn_rsqf(d), 1.0f);
            float r0 = rr0 - rr0 * rinv;
            float r1 = rr1 - rr1 * rinv;
            sN  = 2.f * x  - x2v;
            t0N = 2.f * r0 - r20v;
            t1N = 2.f * r1 - r21v;
            if (J >= 3 && J <= HS + 2) {
                __half2 lo2 = __floats2half2_rn(x2v + RHOf * (x - x2v),
                                                r20v + RHOf * (r0 - r20v));
                unsigned r1b = (unsigned)__half_as_ushort(
                    __float2half(r21v + RHOf * (r1 - r21v)));
                uint2 st; st.x = *(unsigned*)&lo2; st.y = r1b | (yraw << 16);
                fmid[(J + 1) & 3] = st;
            }
        } else { sN = 0.f; t0N = 0.f; t1N = 0.f; }

        {
            float sPrev  = sr[J & 1];
            float t1Prev = t1r[J & 1];
            float hDm1   = (rp < HH) ? 1.f : 0.f;
            v0r[(J + 3) & 3] = mB * (SD(sN) - sN) - t0N;
            v1r[J & 1]       = hDm1 * (sN - sPrev) - t1Prev;
            sr[(J + 1) & 1]  = sN;
            t1r[(J + 1) & 1] = t1N;
        }

        if (J >= 3) {
            const int ro = R0p - 3 + J;
            float hD  = (ro < HH - 1) ? 1.f : 0.f;
            float v0c = v0r[(J + 1) & 3], v0u = v0r[J & 3];
            float v1c = v1r[(J + 1) & 1], v1d = v1r[J & 1];
            float v0l = SUp(v0c);
            float v1l = SUp(v1c);
            float G0 = v0c - v0u;
            float G1 = mA * (v0c - v0l);
            float G2 = v1c - mA * v1l;
            float G3 = hD * (v1d - v1c);
            const int us = (J + 1) & 3;
            float u0v = uf0[us], u1v = uf1[us], u2v = uf2[us], u3v = uf3[us];
            float uu0 = u0v + SIGMAf * G0;
            float uu1 = u1v + SIGMAf * G1;
            float uu2 = u2v + SIGMAf * G2;
            float uu3 = u3v + SIGMAf * G3;
            float d = uu0*uu0 + uu1*uu1 + uu2*uu2 + uu3*uu3;
            float ui = fminf(l2_ * __builtin_amdgcn_rsqf(d), 1.0f);
            uint2 st; st.x = 0u; st.y = 0u;
            if (((unsigned)ro) < (unsigned)HH) {
                __half2 lo = __floats2half2_rn(u0v + RHOf * (uu0 * ui - u0v),
                                               u1v + RHOf * (uu1 * ui - u1v));
                __half2 hi = __floats2half2_rn(u2v + RHOf * (uu2 * ui - u2v),
                                               u3v + RHOf * (uu3 * ui - u3v));
                st.x = *(unsigned*)&lo; st.y = *(unsigned*)&hi;
            }
            cunpk((J + 3) & 3, st);
        }

        if (J == 5) ccompI(R0 - 1, 1, 3, 0, 2);
        if (J >= 6) {
            const int kc = J - 6;
            const int rc = R0 + kc;
            ccompI(rc, kc & 1, kc & 3, (kc + 1) & 3, (kc + 3) & 3);
            uint2 fm = fmid[(J + 2) & 3];
            __half2 mlo = *(reinterpret_cast<__half2*>(&fm.x));
            __half2 mhi = *(reinterpret_cast<__half2*>(&fm.y));
            float cx2 = __low2float(mlo);
            float cyv = __high2float(mhi);
            float hD = (rc < HH - 1) ? 1.f : 0.f;
            float i0c = ci0[kc & 1], i1c = ci1[kc & 1], i1u = ci1[(kc + 1) & 1];
            float i0l = SUp(i0c);
            float na = TAUf * (mA * i0l - mB * i0c + i1u - hD * i1c);
            float x = (cx2 - na + TAUf * cyv) * INV1PT;
            if (cokC) xout[boff + rc * WW + w] = cx2 + RHOf * (x - cx2);
        }
    }
}

extern "C" void kernel_launch(void* const* d_in, const int* in_sizes, int n_in,
                              void* d_out, int out_size, void* d_ws, size_t ws_size,
                              hipStream_t stream)
{
    const float* y   = (const float*)d_in[0];
    const int*   ths = (const int*)d_in[1];
    uint2* ws2 = (uint2*)d_ws;

    uint2* FA = ws2;
    uint2* UA = ws2 + (size_t)NPIX;
    uint2* FB = ws2 + 2 * (size_t)NPIX;
    uint2* UB = ws2 + 3 * (size_t)NPIX;
    float* xout = (float*)d_out;

    // iters 0+1 fused -> state1 in A
    fused01<<<dim3(NBLK), dim3(256), 0, stream>>>(y, ths, FA, UA);
    // iters 2..7: 6 mid dispatches, 2 px/lane
    uint2 *fi = FA, *ui = UA, *fo = FB, *uo = UB;
    for (int it = 2; it <= 7; ++it) {
        sweep2<<<dim3(NBLK2), dim3(128), 0, stream>>>(ths, fi, ui, fo, uo);
        uint2* t;
        t = fi; fi = fo; fo = t;
        t = ui; ui = uo; uo = t;
    }
    // iters 8+9 fused -> xout
    fused89<<<dim3(NBLK), dim3(256), 0, stream>>>(ths, fi, ui, xout);
}

// Round 20
// 137.514 us; speedup vs baseline: 1.0367x; 1.0367x over previous
//
#include <hip/hip_runtime.h>
#include <hip/hip_fp16.h>
#include <math.h>

#define HH 512
#define WW 512
#define BB 4
#define NPIX (BB * HH * WW)

#define HS 4                 // core rows per wave
#define NSX 9                // sweep strips: 9 x 60; fused01/fused89: 9 x 58
#define NBAND (HH / HS)      // 128
#define NWAVES (NSX * NBAND * BB)   // 4608
#define NBLK (NWAVES / 4)           // 1152
#define BPR (NBLK / 8)              // 144 blocks per XCD-region

constexpr float TAUf   = 0.01f;
constexpr float RHOf   = 1.99f;
constexpr float SIGMAf = (float)(1.0 / 0.01 / 72.0);
constexpr float INV1PT = (float)(1.0 / 1.01);

__device__ __forceinline__ float SD(float v) { return __shfl_down(v, 1, 64); }    // lane+1
__device__ __forceinline__ unsigned SDu(unsigned v) { return __shfl_down(v, 1, 64); }
__device__ __forceinline__ float SUp(float v) { return __shfl_up(v, 1, 64); }     // lane-1

// XCD-locality swizzle: with blockIdx % 8 -> XCD round-robin, XCD r owns the
// SAME contiguous 64-band (256-row) slab every dispatch, so the F/u ping-pong
// stays in that XCD's private 4 MB L2 across iterations. (+15 us, R17)
__device__ __forceinline__ int swiz_wid(int bid, int tid) {
    return (((bid & 7) * BPR) + (bid >> 3)) * 4 + (tid >> 6);
}

// F record (uint2): .x = half2(x2, r0), .y = half2(r1, y_half)
// u record (uint2): .x = half2(u0, u1), .y = half2(u2, u3)

// MODE: 1 = mid iter; 2 = last iter (x-only, f32 out)
template <int MODE>
__global__ __launch_bounds__(256) void sweep(
    const float* __restrict__ y, const int* __restrict__ ths_p,
    const uint2* __restrict__ f_in, const uint2* __restrict__ u_in,
    uint2* __restrict__ f_out, uint2* __restrict__ u_out,
    float* __restrict__ xout)
{
    const int tid  = threadIdx.x;
    const int lane = tid & 63;
    const int wid  = swiz_wid(blockIdx.x, tid);
    const int sx   = wid % NSX;
    const int t2   = wid / NSX;
    const int band = t2 & (NBAND - 1);
    const int b    = t2 / NBAND;
    const int R0   = band * HS;
    const int w    = sx * 60 - 2 + lane;
    const int boff = b * (HH * WW);
    const bool wok = ((unsigned)w) < (unsigned)WW;
    const float mA = (w >= 1 && w < WW) ? 1.f : 0.f;
    const float mB = (w >= 0 && w < WW - 1) ? 1.f : 0.f;
    const bool cok = (lane >= 2) && (lane < 62) && (w < WW);

    const float ths  = (float)ths_p[0];
    const float tl1_ = TAUf * (ths * 0.1f);
    const float l2_  = ths * 0.15f;

    float uf0[4], uf1[4], uf2[4], uf3[4];
    unsigned u12r[4];
    float i0r[2], i1r[2];
    float sr[2], t1r[2];
    float v0r[4], v1r[2];
    #pragma unroll
    for (int q = 0; q < 4; ++q) { uf0[q]=uf1[q]=uf2[q]=uf3[q]=0.f; v0r[q]=0.f; u12r[q]=0u; }
    i0r[0]=i0r[1]=i1r[0]=i1r[1]=0.f;
    sr[0]=sr[1]=0.f; t1r[0]=t1r[1]=0.f; v1r[0]=v1r[1]=0.f;

    auto uload = [&](int row) -> uint2 {
        uint2 z; z.x = 0u; z.y = 0u;
        if (((unsigned)row) < (unsigned)HH && wok)
            z = u_in[(size_t)(boff + row * WW + w)];
        return z;
    };
    auto fload = [&](int row) -> uint2 {
        uint2 z; z.x = 0u; z.y = 0u;
        if (((unsigned)row) < (unsigned)HH && wok)
            z = f_in[(size_t)(boff + row * WW + w)];
        return z;
    };
    auto unpk = [&](int slot, uint2 raw) {
        __half2 lo = *(reinterpret_cast<__half2*>(&raw.x));
        __half2 hi = *(reinterpret_cast<__half2*>(&raw.y));
        uf0[slot] = __low2float(lo); uf1[slot] = __high2float(lo);
        uf2[slot] = __low2float(hi); uf3[slot] = __high2float(hi);
        u12r[slot] = (raw.x >> 16) | (raw.y << 16);
    };
    auto compI = [&](int rr, int islot, int c, int d, int uu_) {
        if (((unsigned)rr) < (unsigned)HH) {
            float hD  = (rr < HH - 1) ? 1.f : 0.f;
            unsigned pp = SDu(u12r[c]);
            __half2 ph = *(reinterpret_cast<__half2*>(&pp));
            float u1n = __low2float(ph);
            float u2n = __high2float(ph);
            i0r[islot] = uf0[c] - uf0[d] - u1n + mA * uf1[c];
            i1r[islot] = uf2[c] - u2n - hD * uf3[c] + uf3[uu_];
        } else { i0r[islot] = 0.f; i1r[islot] = 0.f; }
    };

    if (MODE == 2) {
        unpk(2, uload(R0 - 2));
        unpk(3, uload(R0 - 1));
        unpk(0, uload(R0));
        compI(R0 - 1, 1, 3, 0, 2);
        uint2 puA = uload(R0 + 1);
        uint2 puB = uload(R0 + 2);
        uint2 pfA = fload(R0);
        uint2 pfB = fload(R0 + 1);
        #pragma unroll
        for (int k = 0; k < HS; ++k) {
            const int rr = R0 + k;
            unpk((k + 1) & 3, puA);
            puA = puB;
            if (k < HS - 2) puB = uload(R0 + k + 3);
            __half2 lo = *(reinterpret_cast<__half2*>(&pfA.x));
            __half2 hi = *(reinterpret_cast<__half2*>(&pfA.y));
            float x2v = __low2float(lo);
            float yv  = __high2float(hi);
            pfA = pfB;
            if (k < HS - 2) pfB = fload(R0 + k + 2);
            compI(rr, k & 1, k & 3, (k + 1) & 3, (k + 3) & 3);
            float hD = (rr < HH - 1) ? 1.f : 0.f;
            float i0c = i0r[k & 1], i1c = i1r[k & 1], i1u = i1r[(k + 1) & 1];
            float i0l = SUp(i0c);
            float na = TAUf * (mA * i0l - mB * i0c + i1u - hD * i1c);
            float x = (x2v - na + TAUf * yv) * INV1PT;
            if (cok) xout[boff + rr * WW + w] = x2v + RHOf * (x - x2v);
        }
        return;
    }

    auto compS = [&](int rr, int isc, int isp,
                     float yv, float x2v, float r20v, float r21v, unsigned yraw,
                     bool coreRow, float &sOut, float &t0Out, float &t1Out) {
        if (((unsigned)rr) < (unsigned)HH) {
            float hD = (rr < HH - 1) ? 1.f : 0.f;
            float i0c = i0r[isc], i1c = i1r[isc], i1u = i1r[isp];
            float i0l = SUp(i0c);
            float na = TAUf * (mA * i0l - mB * i0c + i1u - hD * i1c);
            float x = (x2v - na + TAUf * yv) * INV1PT;
            float rr0 = r20v + TAUf * i0c;
            float rr1 = r21v + TAUf * i1c;
            float d = rr0 * rr0 + rr1 * rr1;
            float rinv = fminf(tl1_ * __builtin_amdgcn_rsqf(d), 1.0f);
            float r0 = rr0 - rr0 * rinv;
            float r1 = rr1 - rr1 * rinv;
            sOut  = 2.f * x  - x2v;
            t0Out = 2.f * r0 - r20v;
            t1Out = 2.f * r1 - r21v;
            if (coreRow && cok) {
                int idx = boff + rr * WW + w;
                __half2 lo2 = __floats2half2_rn(x2v + RHOf * (x - x2v),
                                                r20v + RHOf * (r0 - r20v));
                unsigned r1b = (unsigned)__half_as_ushort(
                    __float2half(r21v + RHOf * (r1 - r21v)));
                uint2 st; st.x = *(unsigned*)&lo2; st.y = r1b | (yraw << 16);
                f_out[(size_t)idx] = st;
            }
        } else { sOut = 0.f; t0Out = 0.f; t1Out = 0.f; }
    };

    auto compU = [&](int ro, int v0c_s, int v0u_s, int v1c_s, int v1d_s, int uslot) {
        float hD  = (ro < HH - 1) ? 1.f : 0.f;
        float v0c = v0r[v0c_s], v0u = v0r[v0u_s];
        float v1c = v1r[v1c_s], v1d = v1r[v1d_s];
        float v0l = SUp(v0c);
        float v1l = SUp(v1c);
        float G0 = v0c - v0u;
        float G1 = mA * (v0c - v0l);
        float G2 = v1c - mA * v1l;
        float G3 = hD * (v1d - v1c);
        float u0v = uf0[uslot], u1v = uf1[uslot], u2v = uf2[uslot], u3v = uf3[uslot];
        float uu0 = u0v + SIGMAf * G0;
        float uu1 = u1v + SIGMAf * G1;
        float uu2 = u2v + SIGMAf * G2;
        float uu3 = u3v + SIGMAf * G3;
        float d = uu0 * uu0 + uu1 * uu1 + uu2 * uu2 + uu3 * uu3;
        float ui = fminf(l2_ * __builtin_amdgcn_rsqf(d), 1.0f);
        if (cok) {
            int idx = boff + ro * WW + w;
            __half2 lo = __floats2half2_rn(u0v + RHOf * (uu0 * ui - u0v),
                                           u1v + RHOf * (uu1 * ui - u1v));
            __half2 hi = __floats2half2_rn(u2v + RHOf * (uu2 * ui - u2v),
                                           u3v + RHOf * (uu3 * ui - u3v));
            uint2 st; st.x = *(unsigned*)&lo; st.y = *(unsigned*)&hi;
            u_out[(size_t)idx] = st;
        }
    };

    uint2 puA, puB, pfA, pfB;
    puA.x = puA.y = puB.x = puB.y = 0u;
    pfA.x = pfA.y = pfB.x = pfB.y = 0u;
    unpk(1, uload(R0 - 3));
    unpk(2, uload(R0 - 2));
    unpk(3, uload(R0 - 1));
    compI(R0 - 2, 0, 2, 3, 1);
    puA = uload(R0);
    puB = uload(R0 + 1);
    pfA = fload(R0 - 1);
    pfB = fload(R0);

    #pragma unroll
    for (int k = 0; k < HS + 3; ++k) {
        const int rr = R0 - 1 + k;
        unpk(k & 3, puA);
        puA = puB;
        if (k <= HS) puB = uload(R0 + k + 2);
        __half2 lo = *(reinterpret_cast<__half2*>(&pfA.x));
        __half2 hi = *(reinterpret_cast<__half2*>(&pfA.y));
        float x2v  = __low2float(lo);
        float r20v = __high2float(lo);
        float r21v = __low2float(hi);
        float yv   = __high2float(hi);
        unsigned yraw = pfA.y >> 16;
        pfA = pfB;
        if (k <= HS) pfB = fload(R0 + k + 1);

        compI(rr, (k + 1) & 1, (k + 3) & 3, k & 3, (k + 2) & 3);

        float sN, t0N, t1N;
        compS(rr, (k + 1) & 1, k & 1, yv, x2v, r20v, r21v, yraw,
              (k >= 1 && k <= HS), sN, t0N, t1N);

        {
            float sPrev  = sr[k & 1];
            float t1Prev = t1r[k & 1];
            float hDm1   = (rr < HH) ? 1.f : 0.f;
            v0r[(k + 3) & 3] = mB * (SD(sN) - sN) - t0N;
            v1r[k & 1]       = hDm1 * (sN - sPrev) - t1Prev;
            sr[(k + 1) & 1]  = sN;
            t1r[(k + 1) & 1] = t1N;
        }

        if (k >= 3) compU(R0 - 3 + k, (k + 1) & 3, k & 3, (k + 1) & 1, k & 1,
                          (k + 1) & 3);
    }
}

// ---------------------------------------------------------------------------
// fused01: iterations 0 (analytic) + 1. 58-col cores (lanes 3..60).
// ---------------------------------------------------------------------------
__global__ __launch_bounds__(256) void fused01(
    const float* __restrict__ y, const int* __restrict__ ths_p,
    uint2* __restrict__ f_out, uint2* __restrict__ u_out)
{
    const int tid  = threadIdx.x;
    const int lane = tid & 63;
    const int wid  = swiz_wid(blockIdx.x, tid);
    const int sx   = wid % NSX;
    const int t2   = wid / NSX;
    const int band = t2 & (NBAND - 1);
    const int b    = t2 / NBAND;
    const int R0   = band * HS;
    const int w    = sx * 58 - 3 + lane;
    const int boff = b * (HH * WW);
    const bool wok = ((unsigned)w) < (unsigned)WW;
    const float mA = (w >= 1 && w < WW) ? 1.f : 0.f;
    const float mB = (w >= 0 && w < WW - 1) ? 1.f : 0.f;
    const bool cok = (lane >= 3) && (lane <= 60) && (w < WW);

    const float ths  = (float)ths_p[0];
    const float tl1_ = TAUf * (ths * 0.1f);
    const float l2_  = ths * 0.15f;

    float p0r[4];
    float p1r[2];
    float yD1 = 0.f, yD2 = 0.f, yD3 = 0.f;

    float uf0[4], uf1[4], uf2[4], uf3[4];
    unsigned u12r[4];
    float i0r[2], i1r[2];
    float sr[2], t1r[2];
    float v0r[4], v1r[2];
    #pragma unroll
    for (int q = 0; q < 4; ++q) {
        uf0[q]=uf1[q]=uf2[q]=uf3[q]=0.f; v0r[q]=0.f; u12r[q]=0u; p0r[q]=0.f;
    }
    i0r[0]=i0r[1]=i1r[0]=i1r[1]=0.f;
    sr[0]=sr[1]=0.f; t1r[0]=t1r[1]=0.f; v1r[0]=v1r[1]=0.f; p1r[0]=p1r[1]=0.f;

    auto yload = [&](int row) -> float {
        return (((unsigned)row) < (unsigned)HH && wok)
                   ? y[boff + row * WW + w] : 0.f;
    };
    auto unpk = [&](int slot, uint2 raw) {
        __half2 lo = *(reinterpret_cast<__half2*>(&raw.x));
        __half2 hi = *(reinterpret_cast<__half2*>(&raw.y));
        uf0[slot] = __low2float(lo); uf1[slot] = __high2float(lo);
        uf2[slot] = __low2float(hi); uf3[slot] = __high2float(hi);
        u12r[slot] = (raw.x >> 16) | (raw.y << 16);
    };
    auto compI = [&](int rr, int islot, int c, int d, int uu_) {
        if (((unsigned)rr) < (unsigned)HH) {
            float hD  = (rr < HH - 1) ? 1.f : 0.f;
            unsigned pp = SDu(u12r[c]);
            __half2 ph = *(reinterpret_cast<__half2*>(&pp));
            float u1n = __low2float(ph);
            float u2n = __high2float(ph);
            i0r[islot] = uf0[c] - uf0[d] - u1n + mA * uf1[c];
            i1r[islot] = uf2[c] - u2n - hD * uf3[c] + uf3[uu_];
        } else { i0r[islot] = 0.f; i1r[islot] = 0.f; }
    };

    float pyA = yload(R0 - 4);
    float pyB = yload(R0 - 3);

    #pragma unroll
    for (int j = 0; j < HS + 9; ++j) {
        const int p = R0 - 4 + j;
        float yp = pyA; pyA = pyB;
        if (j <= HS + 6) pyB = yload(R0 - 2 + j);

        p0r[j & 3]       = mB * (SD(yp) - yp);
        p1r[(j + 1) & 1] = ((p < HH) ? 1.f : 0.f) * (yp - yD1);

        if (j >= 3) {
            const int ro = R0 - 6 + j;
            float hD  = (ro < HH - 1) ? 1.f : 0.f;
            float v0c = p0r[(j + 2) & 3], v0u = p0r[(j + 1) & 3];
            float v1c = p1r[j & 1],       v1d = p1r[(j + 1) & 1];
            float G0 = v0c - v0u;
            float G1 = mA * (v0c - SUp(v0c));
            float G2 = v1c - mA * SUp(v1c);
            float G3 = hD * (v1d - v1c);
            float uu0 = SIGMAf * G0, uu1 = SIGMAf * G1;
            float uu2 = SIGMAf * G2, uu3 = SIGMAf * G3;
            float d = uu0*uu0 + uu1*uu1 + uu2*uu2 + uu3*uu3;
            float ui = fminf(l2_ * __builtin_amdgcn_rsqf(d), 1.0f);
            __half2 lo = __floats2half2_rn(RHOf * (uu0 * ui), RHOf * (uu1 * ui));
            __half2 hi = __floats2half2_rn(RHOf * (uu2 * ui), RHOf * (uu3 * ui));
            uint2 st; st.x = *(unsigned*)&lo; st.y = *(unsigned*)&hi;
            unpk((j + 2) & 3, st);
        }

        if (j == 5) compI(R0 - 2, 0, 2, 3, 1);

        if (j >= 6) {
            const int k  = j - 6;
            const int rr = R0 - 1 + k;
            __half yh = __float2half(yD3);
            float yv  = __half2float(yh);
            unsigned yraw = (unsigned)__half_as_ushort(yh);

            compI(rr, (k + 1) & 1, (k + 3) & 3, k & 3, (k + 2) & 3);

            float sN, t0N, t1N;
            {
                const bool coreRow = (k >= 1 && k <= HS);
                if (((unsigned)rr) < (unsigned)HH) {
                    float hD = (rr < HH - 1) ? 1.f : 0.f;
                    float i0c = i0r[(k + 1) & 1], i1c = i1r[(k + 1) & 1];
                    float i1u = i1r[k & 1];
                    float i0l = SUp(i0c);
                    float na = TAUf * (mA * i0l - mB * i0c + i1u - hD * i1c);
                    float x = (yv - na + TAUf * yv) * INV1PT;
                    float rr0 = TAUf * i0c;
                    float rr1 = TAUf * i1c;
                    float d2 = rr0*rr0 + rr1*rr1;
                    float rinv = fminf(tl1_ * __builtin_amdgcn_rsqf(d2), 1.0f);
                    float r0 = rr0 - rr0 * rinv;
                    float r1 = rr1 - rr1 * rinv;
                    sN  = 2.f * x - yv;
                    t0N = 2.f * r0;
                    t1N = 2.f * r1;
                    if (coreRow && cok) {
                        int idx = boff + rr * WW + w;
                        __half2 lo2 = __floats2half2_rn(yv + RHOf * (x - yv),
                                                        RHOf * r0);
                        unsigned r1b = (unsigned)__half_as_ushort(
                            __float2half(RHOf * r1));
                        uint2 st2; st2.x = *(unsigned*)&lo2;
                        st2.y = r1b | (yraw << 16);
                        f_out[(size_t)idx] = st2;
                    }
                } else { sN = 0.f; t0N = 0.f; t1N = 0.f; }
            }

            {
                float sPrev  = sr[k & 1];
                float t1Prev = t1r[k & 1];
                float hDm1   = (rr < HH) ? 1.f : 0.f;
                v0r[(k + 3) & 3] = mB * (SD(sN) - sN) - t0N;
                v1r[k & 1]       = hDm1 * (sN - sPrev) - t1Prev;
                sr[(k + 1) & 1]  = sN;
                t1r[(k + 1) & 1] = t1N;
            }

            if (k >= 3) {
                const int ro = R0 - 3 + k;
                float hD  = (ro < HH - 1) ? 1.f : 0.f;
                float v0c = v0r[(k + 1) & 3], v0u = v0r[k & 3];
                float v1c = v1r[(k + 1) & 1], v1d = v1r[k & 1];
                float v0l = SUp(v0c);
                float v1l = SUp(v1c);
                float G0 = v0c - v0u;
                float G1 = mA * (v0c - v0l);
                float G2 = v1c - mA * v1l;
                float G3 = hD * (v1d - v1c);
                const int us = (k + 1) & 3;
                float u0v = uf0[us], u1v = uf1[us], u2v = uf2[us], u3v = uf3[us];
                float uu0 = u0v + SIGMAf * G0;
                float uu1 = u1v + SIGMAf * G1;
                float uu2 = u2v + SIGMAf * G2;
                float uu3 = u3v + SIGMAf * G3;
                float d = uu0*uu0 + uu1*uu1 + uu2*uu2 + uu3*uu3;
                float ui = fminf(l2_ * __builtin_amdgcn_rsqf(d), 1.0f);
                if (cok) {
                    int idx = boff + ro * WW + w;
                    __half2 lo = __floats2half2_rn(u0v + RHOf * (uu0 * ui - u0v),
                                                   u1v + RHOf * (uu1 * ui - u1v));
                    __half2 hi = __floats2half2_rn(u2v + RHOf * (uu2 * ui - u2v),
                                                   u3v + RHOf * (uu3 * ui - u3v));
                    uint2 st; st.x = *(unsigned*)&lo; st.y = *(unsigned*)&hi;
                    u_out[(size_t)idx] = st;
                }
            }
        }

        yD3 = yD2; yD2 = yD1; yD1 = yp;
    }
}

// ---------------------------------------------------------------------------
// fused89: iter 8 (full mid, producer P) + iter 9 (x-only, consumer C).
// ---------------------------------------------------------------------------
__global__ __launch_bounds__(256) void fused89(
    const int* __restrict__ ths_p,
    const uint2* __restrict__ f_in, const uint2* __restrict__ u_in,
    float* __restrict__ xout)
{
    const int tid  = threadIdx.x;
    const int lane = tid & 63;
    const int wid  = swiz_wid(blockIdx.x, tid);
    const int sx   = wid % NSX;
    const int t2   = wid / NSX;
    const int band = t2 & (NBAND - 1);
    const int b    = t2 / NBAND;
    const int R0   = band * HS;
    const int R0p  = R0 - 2;
    const int w    = sx * 58 - 3 + lane;
    const int boff = b * (HH * WW);
    const bool wok = ((unsigned)w) < (unsigned)WW;
    const float mA = (w >= 1 && w < WW) ? 1.f : 0.f;
    const float mB = (w >= 0 && w < WW - 1) ? 1.f : 0.f;
    const bool cokC = (lane >= 3) && (lane <= 60) && (w < WW);

    const float ths  = (float)ths_p[0];
    const float tl1_ = TAUf * (ths * 0.1f);
    const float l2_  = ths * 0.15f;

    constexpr int HSp = HS + 3;   // 7

    float uf0[4], uf1[4], uf2[4], uf3[4];
    unsigned u12r[4];
    float i0r[2], i1r[2];
    float sr[2], t1r[2];
    float v0r[4], v1r[2];
    float cf0[4], cf1[4], cf2[4], cf3[4];
    unsigned c12[4];
    float ci0[2], ci1[2];
    uint2 fmid[4];
    #pragma unroll
    for (int q = 0; q < 4; ++q) {
        uf0[q]=uf1[q]=uf2[q]=uf3[q]=0.f; v0r[q]=0.f; u12r[q]=0u;
        cf0[q]=cf1[q]=cf2[q]=cf3[q]=0.f; c12[q]=0u;
        fmid[q].x = 0u; fmid[q].y = 0u;
    }
    i0r[0]=i0r[1]=i1r[0]=i1r[1]=0.f;
    ci0[0]=ci0[1]=ci1[0]=ci1[1]=0.f;
    sr[0]=sr[1]=0.f; t1r[0]=t1r[1]=0.f; v1r[0]=v1r[1]=0.f;

    auto uload = [&](int row) -> uint2 {
        uint2 z; z.x = 0u; z.y = 0u;
        if (((unsigned)row) < (unsigned)HH && wok)
            z = u_in[(size_t)(boff + row * WW + w)];
        return z;
    };
    auto fload = [&](int row) -> uint2 {
        uint2 z; z.x = 0u; z.y = 0u;
        if (((unsigned)row) < (unsigned)HH && wok)
            z = f_in[(size_t)(boff + row * WW + w)];
        return z;
    };
    auto unpk = [&](int slot, uint2 raw) {
        __half2 lo = *(reinterpret_cast<__half2*>(&raw.x));
        __half2 hi = *(reinterpret_cast<__half2*>(&raw.y));
        uf0[slot] = __low2float(lo); uf1[slot] = __high2float(lo);
        uf2[slot] = __low2float(hi); uf3[slot] = __high2float(hi);
        u12r[slot] = (raw.x >> 16) | (raw.y << 16);
    };
    auto compI = [&](int rr, int islot, int c, int d, int uu_) {
        if (((unsigned)rr) < (unsigned)HH) {
            float hD  = (rr < HH - 1) ? 1.f : 0.f;
            unsigned pp = SDu(u12r[c]);
            __half2 ph = *(reinterpret_cast<__half2*>(&pp));
            float u1n = __low2float(ph);
            float u2n = __high2float(ph);
            i0r[islot] = uf0[c] - uf0[d] - u1n + mA * uf1[c];
            i1r[islot] = uf2[c] - u2n - hD * uf3[c] + uf3[uu_];
        } else { i0r[islot] = 0.f; i1r[islot] = 0.f; }
    };
    auto cunpk = [&](int slot, uint2 raw) {
        __half2 lo = *(reinterpret_cast<__half2*>(&raw.x));
        __half2 hi = *(reinterpret_cast<__half2*>(&raw.y));
        cf0[slot] = __low2float(lo); cf1[slot] = __high2float(lo);
        cf2[slot] = __low2float(hi); cf3[slot] = __high2float(hi);
        c12[slot] = (raw.x >> 16) | (raw.y << 16);
    };
    auto ccompI = [&](int rr, int islot, int c, int d, int uu_) {
        if (((unsigned)rr) < (unsigned)HH) {
            float hD  = (rr < HH - 1) ? 1.f : 0.f;
            unsigned pp = SDu(c12[c]);
            __half2 ph = *(reinterpret_cast<__half2*>(&pp));
            float u1n = __low2float(ph);
            float u2n = __high2float(ph);
            ci0[islot] = cf0[c] - cf0[d] - u1n + mA * cf1[c];
            ci1[islot] = cf2[c] - u2n - hD * cf3[c] + cf3[uu_];
        } else { ci0[islot] = 0.f; ci1[islot] = 0.f; }
    };

    unpk(1, uload(R0p - 3));
    unpk(2, uload(R0p - 2));
    unpk(3, uload(R0p - 1));
    compI(R0p - 2, 0, 2, 3, 1);
    uint2 puA = uload(R0p);
    uint2 puB = uload(R0p + 1);
    uint2 pfA = fload(R0p - 1);
    uint2 pfB = fload(R0p);

    #pragma unroll
    for (int J = 0; J < HSp + 3; ++J) {       // J = 0..9
        const int rp = R0p - 1 + J;

        unpk(J & 3, puA);
        puA = puB;
        if (J <= HSp) puB = uload(R0p + J + 2);
        __half2 flo = *(reinterpret_cast<__half2*>(&pfA.x));
        __half2 fhi = *(reinterpret_cast<__half2*>(&pfA.y));
        float x2v  = __low2float(flo);
        float r20v = __high2float(flo);
        float r21v = __low2float(fhi);
        float yv   = __high2float(fhi);
        unsigned yraw = pfA.y >> 16;
        pfA = pfB;
        if (J <= HSp) pfB = fload(R0p + J + 1);

        compI(rp, (J + 1) & 1, (J + 3) & 3, J & 3, (J + 2) & 3);

        float sN, t0N, t1N;
        if (((unsigned)rp) < (unsigned)HH) {
            float hD = (rp < HH - 1) ? 1.f : 0.f;
            float i0c = i0r[(J + 1) & 1], i1c = i1r[(J + 1) & 1];
            float i1u = i1r[J & 1];
            float i0l = SUp(i0c);
            float na = TAUf * (mA * i0l - mB * i0c + i1u - hD * i1c);
            float x = (x2v - na + TAUf * yv) * INV1PT;
            float rr0 = r20v + TAUf * i0c;
            float rr1 = r21v + TAUf * i1c;
            float d = rr0 * rr0 + rr1 * rr1;
            float rinv = fminf(tl1_ * __builtin_amdgcn_rsqf(d), 1.0f);
            float r0 = rr0 - rr0 * rinv;
            float r1 = rr1 - rr1 * rinv;
            sN  = 2.f * x  - x2v;
            t0N = 2.f * r0 - r20v;
            t1N = 2.f * r1 - r21v;
            if (J >= 3 && J <= HS + 2) {
                __half2 lo2 = __floats2half2_rn(x2v + RHOf * (x - x2v),
                                                r20v + RHOf * (r0 - r20v));
                unsigned r1b = (unsigned)__half_as_ushort(
                    __float2half(r21v + RHOf * (r1 - r21v)));
                uint2 st; st.x = *(unsigned*)&lo2; st.y = r1b | (yraw << 16);
                fmid[(J + 1) & 3] = st;
            }
        } else { sN = 0.f; t0N = 0.f; t1N = 0.f; }

        {
            float sPrev  = sr[J & 1];
            float t1Prev = t1r[J & 1];
            float hDm1   = (rp < HH) ? 1.f : 0.f;
            v0r[(J + 3) & 3] = mB * (SD(sN) - sN) - t0N;
            v1r[J & 1]       = hDm1 * (sN - sPrev) - t1Prev;
            sr[(J + 1) & 1]  = sN;
            t1r[(J + 1) & 1] = t1N;
        }

        if (J >= 3) {
            const int ro = R0p - 3 + J;
            float hD  = (ro < HH - 1) ? 1.f : 0.f;
            float v0c = v0r[(J + 1) & 3], v0u = v0r[J & 3];
            float v1c = v1r[(J + 1) & 1], v1d = v1r[J & 1];
            float v0l = SUp(v0c);
            float v1l = SUp(v1c);
            float G0 = v0c - v0u;
            float G1 = mA * (v0c - v0l);
            float G2 = v1c - mA * v1l;
            float G3 = hD * (v1d - v1c);
            const int us = (J + 1) & 3;
            float u0v = uf0[us], u1v = uf1[us], u2v = uf2[us], u3v = uf3[us];
            float uu0 = u0v + SIGMAf * G0;
            float uu1 = u1v + SIGMAf * G1;
            float uu2 = u2v + SIGMAf * G2;
            float uu3 = u3v + SIGMAf * G3;
            float d = uu0*uu0 + uu1*uu1 + uu2*uu2 + uu3*uu3;
            float ui = fminf(l2_ * __builtin_amdgcn_rsqf(d), 1.0f);
            uint2 st; st.x = 0u; st.y = 0u;
            if (((unsigned)ro) < (unsigned)HH) {
                __half2 lo = __floats2half2_rn(u0v + RHOf * (uu0 * ui - u0v),
                                               u1v + RHOf * (uu1 * ui - u1v));
                __half2 hi = __floats2half2_rn(u2v + RHOf * (uu2 * ui - u2v),
                                               u3v + RHOf * (uu3 * ui - u3v));
                st.x = *(unsigned*)&lo; st.y = *(unsigned*)&hi;
            }
            cunpk((J + 3) & 3, st);
        }

        if (J == 5) ccompI(R0 - 1, 1, 3, 0, 2);
        if (J >= 6) {
            const int kc = J - 6;
            const int rc = R0 + kc;
            ccompI(rc, kc & 1, kc & 3, (kc + 1) & 3, (kc + 3) & 3);
            uint2 fm = fmid[(J + 2) & 3];
            __half2 mlo = *(reinterpret_cast<__half2*>(&fm.x));
            __half2 mhi = *(reinterpret_cast<__half2*>(&fm.y));
            float cx2 = __low2float(mlo);
            float cyv = __high2float(mhi);
            float hD = (rc < HH - 1) ? 1.f : 0.f;
            float i0c = ci0[kc & 1], i1c = ci1[kc & 1], i1u = ci1[(kc + 1) & 1];
            float i0l = SUp(i0c);
            float na = TAUf * (mA * i0l - mB * i0c + i1u - hD * i1c);
            float x = (cx2 - na + TAUf * cyv) * INV1PT;
            if (cokC) xout[boff + rc * WW + w] = cx2 + RHOf * (x - cx2);
        }
    }
}

extern "C" void kernel_launch(void* const* d_in, const int* in_sizes, int n_in,
                              void* d_out, int out_size, void* d_ws, size_t ws_size,
                              hipStream_t stream)
{
    const float* y   = (const float*)d_in[0];
    const int*   ths = (const int*)d_in[1];
    uint2* ws2 = (uint2*)d_ws;

    uint2* FA = ws2;
    uint2* UA = ws2 + (size_t)NPIX;
    uint2* FB = ws2 + 2 * (size_t)NPIX;
    uint2* UB = ws2 + 3 * (size_t)NPIX;
    float* xout = (float*)d_out;

    dim3 block(256);
    dim3 grid(NBLK);

    // iters 0+1 fused -> A
    fused01<<<grid, block, 0, stream>>>(y, ths, FA, UA);
    // iters 2..7: 6 mid dispatches
    uint2 *fi = FA, *ui = UA, *fo = FB, *uo = UB;
    for (int it = 2; it <= 7; ++it) {
        sweep<1><<<grid, block, 0, stream>>>(y, ths, fi, ui, fo, uo, nullptr);
        uint2* t;
        t = fi; fi = fo; fo = t;
        t = ui; ui = uo; uo = t;
    }
    // iters 8+9 fused -> xout
    fused89<<<grid, block, 0, stream>>>(ths, fi, ui, xout);
}